// Round 12
// baseline (1648.732 us; speedup 1.0000x reference)
//
#include <hip/hip_runtime.h>
#include <hip/hip_bf16.h>
#include <math.h>

#define BATCH 8
#define HH 1024
#define WW 1024
#define NB 768  // persistent blocks; capacity >=1024 guaranteed (see launch_bounds note)

__device__ __forceinline__ int reflect1024(int i) {
    i = i < 0 ? -i : i;
    return i > 1023 ? 2046 - i : i;
}

// ---------------------------------------------------------------------------
// software grid barrier (generation/counter), device-scope.
// Safe because: all NB blocks co-resident (LDS 31.5KB*4<160KB, VGPR<=128 via
// __launch_bounds__(256,4) => >=4 blocks/CU => capacity >=1024 > 768) and
// __threadfence() emits agent-scope wbL2/invL2 on gfx950 (cross-XCD).
// ---------------------------------------------------------------------------
__device__ __forceinline__ void gridbar(unsigned int* cnt, unsigned int* gen) {
    __syncthreads();
    if (threadIdx.x == 0) {
        __threadfence();
        unsigned int g = atomicAdd(gen, 0u);
        unsigned int a = atomicAdd(cnt, 1u);
        if (a == NB - 1) {
            atomicExch(cnt, 0u);
            __threadfence();
            atomicAdd(gen, 1u);
        } else {
            while (atomicAdd(gen, 0u) == g) __builtin_amdgcn_s_sleep(16);
        }
        __threadfence();
    }
    __syncthreads();
}

// ---------------------------------------------------------------------------
// stage bodies (all R7/R10/R11-verified logic, device-fn form)
// ---------------------------------------------------------------------------
__device__ __forceinline__ void dev_conv0(int idx,
                                          const float* __restrict__ lqs,
                                          const float* __restrict__ evs,
                                          const float* __restrict__ w,
                                          const float* __restrict__ bias,
                                          float* __restrict__ out) {
    int q = idx & 4095;
    int b = idx >> 12;
    int qx = q & 31, oy = q >> 5;
    int iy0 = oy * 2 - 1;

    float acc[4][8];
#pragma unroll
    for (int j = 0; j < 4; ++j)
#pragma unroll
        for (int o = 0; o < 8; ++o) acc[j][o] = bias[o];

#pragma unroll
    for (int ic = 0; ic < 3; ++ic) {
        const float* ipc = lqs + (size_t)(b * 3 + ic) * HH * WW;
#pragma unroll
        for (int ky = 0; ky < 3; ++ky) {
            int iy = iy0 + ky;
            if (iy < 0) continue;
            const float* row = ipc + (size_t)iy * 4 * WW;
            float xr[9];
#pragma unroll
            for (int i = 0; i < 9; ++i) {
                int ix = 8 * qx - 1 + i;
                xr[i] = (ix >= 0) ? row[ix * 4] : 0.0f;
            }
#pragma unroll
            for (int o = 0; o < 8; ++o) {
                const float* wp = w + (o * 18 + ic) * 9 + ky * 3;
#pragma unroll
                for (int j = 0; j < 4; ++j)
#pragma unroll
                    for (int kx = 0; kx < 3; ++kx)
                        acc[j][o] = fmaf(wp[kx], xr[2 * j + kx], acc[j][o]);
            }
        }
    }
    for (int ic = 0; ic < 15; ++ic) {
        const float* ipc = evs + (size_t)(b * 15 + ic) * 65536;
#pragma unroll
        for (int ky = 0; ky < 3; ++ky) {
            int iy = iy0 + ky;
            if (iy < 0) continue;
            const float* row = ipc + iy * 256;
            const float4* r4 = (const float4*)row;
            float4 A = r4[2 * qx];
            float4 Bv = r4[2 * qx + 1];
            float m = (qx > 0) ? row[8 * qx - 1] : 0.0f;
            float xr[9] = {m, A.x, A.y, A.z, A.w, Bv.x, Bv.y, Bv.z, Bv.w};
#pragma unroll
            for (int o = 0; o < 8; ++o) {
                const float* wp = w + (o * 18 + ic + 3) * 9 + ky * 3;
#pragma unroll
                for (int j = 0; j < 4; ++j)
#pragma unroll
                    for (int kx = 0; kx < 3; ++kx)
                        acc[j][o] = fmaf(wp[kx], xr[2 * j + kx], acc[j][o]);
            }
        }
    }
#pragma unroll
    for (int o = 0; o < 8; ++o) {
        float4 v = make_float4(fmaxf(acc[0][o], 0.0f), fmaxf(acc[1][o], 0.0f),
                               fmaxf(acc[2][o], 0.0f), fmaxf(acc[3][o], 0.0f));
        *(float4*)(out + ((size_t)(b * 8 + o) << 14) + oy * 128 + qx * 4) = v;
    }
}

template <int IC, int OC, int OCT, int IH, int IW, int STRIDE, bool RELU, bool HASB>
__device__ __forceinline__ void dev_convN(int idx,
                                          const float* __restrict__ in,
                                          const float* __restrict__ w,
                                          const float* __restrict__ bias,
                                          float* __restrict__ out) {
    constexpr int OH = (IH + 2 - 3) / STRIDE + 1;
    constexpr int OW = (IW + 2 - 3) / STRIDE + 1;
    constexpr int POS = OH * OW;
    constexpr int G = OC / OCT;
    if (idx >= BATCH * G * POS) return;
    int px = idx % POS;
    int g = (idx / POS) % G;
    int b = idx / (POS * G);
    int ox = px % OW, oy = px / OW;
    int iy0 = oy * STRIDE - 1, ix0 = ox * STRIDE - 1;

    float acc[OCT];
#pragma unroll
    for (int o = 0; o < OCT; ++o) acc[o] = HASB ? bias[g * OCT + o] : 0.0f;

    const float* ip = in + (size_t)b * IC * IH * IW;
    for (int ic = 0; ic < IC; ++ic) {
        const float* ipc = ip + ic * IH * IW;
        float x[9];
#pragma unroll
        for (int ky = 0; ky < 3; ++ky) {
            int iy = iy0 + ky;
#pragma unroll
            for (int kx = 0; kx < 3; ++kx) {
                int ix = ix0 + kx;
                bool ok = (iy >= 0) && (iy < IH) && (ix >= 0) && (ix < IW);
                x[ky * 3 + kx] = ok ? ipc[iy * IW + ix] : 0.0f;
            }
        }
#pragma unroll
        for (int o = 0; o < OCT; ++o) {
            const float* wp = w + ((g * OCT + o) * IC + ic) * 9;
#pragma unroll
            for (int k = 0; k < 9; ++k) acc[o] = fmaf(wp[k], x[k], acc[o]);
        }
    }
#pragma unroll
    for (int o = 0; o < OCT; ++o) {
        float v = acc[o];
        if (RELU) v = fmaxf(v, 0.0f);
        out[(size_t)(b * OC + g * OCT + o) * POS + px] = v;
    }
}

template <int IC, int OC, int OCT, int IH, int IW, int STRIDE, int SPLIT>
__device__ __forceinline__ void dev_convS(int idx,
                                          const float* __restrict__ in,
                                          const float* __restrict__ w,
                                          float* __restrict__ part) {
    constexpr int OH = (IH + 2 - 3) / STRIDE + 1;
    constexpr int OW = (IW + 2 - 3) / STRIDE + 1;
    constexpr int POS = OH * OW;
    constexpr int G = OC / OCT;
    constexpr int TOT = BATCH * G * POS;
    constexpr int ICS = IC / SPLIT;
    constexpr int N = BATCH * OC * POS;
    if (idx >= TOT * SPLIT) return;
    int s = idx / TOT, r = idx % TOT;
    int px = r % POS;
    int g = (r / POS) % G;
    int b = r / (POS * G);
    int ox = px % OW, oy = px / OW;
    int iy0 = oy * STRIDE - 1, ix0 = ox * STRIDE - 1;

    float acc[OCT];
#pragma unroll
    for (int o = 0; o < OCT; ++o) acc[o] = 0.0f;

    const float* ip = in + (size_t)b * IC * IH * IW;
    for (int ic = s * ICS; ic < (s + 1) * ICS; ++ic) {
        const float* ipc = ip + ic * IH * IW;
        float x[9];
#pragma unroll
        for (int ky = 0; ky < 3; ++ky) {
            int iy = iy0 + ky;
#pragma unroll
            for (int kx = 0; kx < 3; ++kx) {
                int ix = ix0 + kx;
                bool ok = (iy >= 0) && (iy < IH) && (ix >= 0) && (ix < IW);
                x[ky * 3 + kx] = ok ? ipc[iy * IW + ix] : 0.0f;
            }
        }
#pragma unroll
        for (int o = 0; o < OCT; ++o) {
            const float* wp = w + ((g * OCT + o) * IC + ic) * 9;
#pragma unroll
            for (int k = 0; k < 9; ++k) acc[o] = fmaf(wp[k], x[k], acc[o]);
        }
    }
#pragma unroll
    for (int o = 0; o < OCT; ++o)
        part[(size_t)s * N + (size_t)(b * OC + g * OCT + o) * POS + px] = acc[o];
}

template <int OC, int POS, int SPLIT, bool RELU, bool HASB>
__device__ __forceinline__ void dev_reduce(int idx,
                                           const float* __restrict__ part,
                                           const float* __restrict__ bias,
                                           float* __restrict__ out) {
    constexpr int N = BATCH * OC * POS;
    if (idx >= N) return;
    int oc = (idx / POS) % OC;
    float a = HASB ? bias[oc] : 0.0f;
#pragma unroll
    for (int s = 0; s < SPLIT; ++s) a += part[(size_t)s * N + idx];
    out[idx] = RELU ? fmaxf(a, 0.0f) : a;
}

// blur+guide for one 64x32 tile; z -> u16 fixed point (x8192).
__device__ __forceinline__ void dev_blur(int tile, int t,
                                         const float* __restrict__ lqs,
                                         const float* __restrict__ gw1,
                                         const float* __restrict__ gb1,
                                         const float* __restrict__ gw2,
                                         const float* __restrict__ gb2,
                                         unsigned short* __restrict__ gq,
                                         float* sm) {
    float* sBH = sm;             // 3*32*81 = 7776
    float* sW1 = sm + 7776;      // 48
    float* sB1 = sW1 + 48;       // 16
    float* sW2 = sB1 + 16;       // 16
    float* sB2v = sW2 + 16;      // 1
    __syncthreads();             // protect smem reuse across works/stages

    int bx = tile & 15;
    int by = (tile >> 4) & 31;
    int b = tile >> 9;
    int x0 = bx * 64, y0 = by * 32;

    float gv[17];
    {
        float gs = 0.0f;
#pragma unroll
        for (int i = 0; i < 17; ++i) {
            float d = (float)i - 8.0f;
            gv[i] = expf(-(d * d) * 0.125f);
            gs += gv[i];
        }
        float inv = 1.0f / gs;
#pragma unroll
        for (int i = 0; i < 17; ++i) gv[i] *= inv;
    }

    if (t < 48) sW1[t] = gw1[t];
    if (t < 16) { sB1[t] = gb1[t]; sW2[t] = gw2[t]; }
    if (t == 0) sB2v[0] = gb2[0];

    if (t < 240) {
        int c = t / 80, xo = t % 80;
        int gx = reflect1024(x0 + xo - 8);
        const float* colp = lqs + (size_t)(b * 3 + c) * HH * WW + gx;
        float win[17];
#pragma unroll
        for (int i = 0; i < 16; ++i)
            win[i] = colp[(size_t)reflect1024(y0 - 8 + i) * WW];
#pragma unroll
        for (int j = 0; j < 32; ++j) {
            win[(16 + j) % 17] = colp[(size_t)reflect1024(y0 + 8 + j) * WW];
            float acc = 0.0f;
#pragma unroll
            for (int i = 0; i < 17; ++i) acc = fmaf(gv[i], win[(j + i) % 17], acc);
            sBH[(c * 32 + j) * 81 + xo] = acc;
        }
    }
    __syncthreads();

    int yy = t >> 3, xs = (t & 7) * 8;
    float bcv[3][8];
#pragma unroll
    for (int c = 0; c < 3; ++c) {
        float win[17];
#pragma unroll
        for (int i = 0; i < 16; ++i) win[i] = sBH[(c * 32 + yy) * 81 + xs + i];
#pragma unroll
        for (int j = 0; j < 8; ++j) {
            win[(16 + j) % 17] = sBH[(c * 32 + yy) * 81 + xs + 16 + j];
            float acc = 0.0f;
#pragma unroll
            for (int i = 0; i < 17; ++i) acc = fmaf(gv[i], win[(j + i) % 17], acc);
            bcv[c][j] = acc;
        }
    }

    unsigned int qw[4];
#pragma unroll
    for (int j = 0; j < 8; ++j) {
        float b0 = bcv[0][j], b1 = bcv[1][j], b2 = bcv[2][j];
        float s = sB2v[0];
#pragma unroll
        for (int c = 0; c < 16; ++c) {
            float g1 = fmaf(sW1[c * 3 + 0], b0,
                       fmaf(sW1[c * 3 + 1], b1,
                       fmaf(sW1[c * 3 + 2], b2, sB1[c])));
            s = fmaf(sW2[c], fmaxf(g1, 0.0f), s);
        }
        float sig = 1.0f / (1.0f + expf(-s));
        float guide = sig * 2.0f - 0.5f;
        float fz = fminf(fmaxf(fmaf(guide, 4.0f, 3.5f), 0.0f), 7.0f);
        unsigned int q = (unsigned int)(fz * 8192.0f + 0.5f);
        if (j & 1) qw[j >> 1] |= (q << 16);
        else qw[j >> 1] = q;
    }
    size_t o = ((size_t)b << 20) + ((size_t)(y0 + yy) << 10) + x0 + xs;
    *(uint4*)(gq + o) = make_uint4(qw[0], qw[1], qw[2], qw[3]);
}

// fc1 work (folds cw1 split-16 reduce): one work = 4 rows of h1 for batch b.
__device__ __forceinline__ void dev_fc1(int w, int t,
                                        const float* __restrict__ partD,
                                        const float* __restrict__ cb1,
                                        const float* __restrict__ fw1,
                                        const float* __restrict__ fb1,
                                        float* __restrict__ h1, float* sm) {
    float* xin = sm;
    __syncthreads();
    int b = w >> 6, rgrp = w & 63;
    int wave = t >> 6, lane = t & 63;

    for (int i = t; i < 1024; i += 256) {
        float v = cb1[i >> 4];
#pragma unroll
        for (int s = 0; s < 16; ++s) v += partD[s * 8192 + b * 1024 + i];
        xin[i] = fmaxf(v, 0.0f);
    }
    __syncthreads();

    int r = (rgrp << 2) | wave;
    const float4* w4 = (const float4*)(fw1 + r * 1024);
    const float4* x4 = (const float4*)xin;
    float acc = 0.0f;
#pragma unroll
    for (int jj = 0; jj < 4; ++jj) {
        float4 wv = w4[lane + 64 * jj];
        float4 xv = x4[lane + 64 * jj];
        acc = fmaf(wv.x, xv.x, acc);
        acc = fmaf(wv.y, xv.y, acc);
        acc = fmaf(wv.z, xv.z, acc);
        acc = fmaf(wv.w, xv.w, acc);
    }
#pragma unroll
    for (int m = 32; m; m >>= 1) acc += __shfl_xor(acc, m, 64);
    if (lane == 0) h1[b * 256 + r] = fmaxf(acc + fb1[r], 0.0f);
}

// fc23+fuse work: one work = (b,d) plane of bg; recomputes h2/xg per block
// (~40K FMA, trivial) — folds lw2's split-8 partials.
__device__ __forceinline__ void dev_fc23fuse(int w, int t,
                                             const float* __restrict__ h1,
                                             const float* __restrict__ fw2,
                                             const float* __restrict__ fb2,
                                             const float* __restrict__ fw3,
                                             const float* __restrict__ fb3,
                                             const float* __restrict__ partC,
                                             const float* __restrict__ fuw,
                                             const float* __restrict__ fub,
                                             float* __restrict__ bg, float* sm) {
    float* h2 = sm;
    float* xg = sm + 128;
    __syncthreads();
    int b = w >> 3, d = w & 7;
    int wave = t >> 6, lane = t & 63;

    float4 xv1 = ((const float4*)(h1 + b * 256))[lane];
#pragma unroll 4
    for (int i = 0; i < 32; ++i) {
        int r = wave * 32 + i;
        float4 wv = ((const float4*)(fw2 + r * 256))[lane];
        float acc = fmaf(wv.x, xv1.x, fmaf(wv.y, xv1.y, fmaf(wv.z, xv1.z, wv.w * xv1.w)));
#pragma unroll
        for (int m = 32; m; m >>= 1) acc += __shfl_xor(acc, m, 64);
        if (lane == 0) h2[r] = fmaxf(acc + fb2[r], 0.0f);
    }
    __syncthreads();

    float2 xv2 = ((const float2*)h2)[lane];
#pragma unroll 4
    for (int i = 0; i < 16; ++i) {
        int r = wave * 16 + i;
        float2 wv = ((const float2*)(fw3 + r * 128))[lane];
        float acc = fmaf(wv.x, xv2.x, wv.y * xv2.y);
#pragma unroll
        for (int m = 32; m; m >>= 1) acc += __shfl_xor(acc, m, 64);
        if (lane == 0) xg[r] = acc + fb3[r];
    }
    __syncthreads();

    int px = t;
    float acc = fub[d];
    for (int c = 0; c < 64; ++c) {
        int base = (b * 64 + c) * 256 + px;
        float xlv = 0.0f;
#pragma unroll
        for (int s = 0; s < 8; ++s) xlv += partC[s * 131072 + base];
        float f = fmaxf(xg[c] + xlv, 0.0f);
        acc = fmaf(fuw[d * 64 + c], f, acc);
    }
    bg[(b * 8 + d) * 256 + px] = acc;
}

// slice work: one work = 2048-px chunk; bg LDS-cached per work.
__device__ __forceinline__ void dev_slice(int w, int t,
                                          const unsigned short* __restrict__ gq,
                                          const float* __restrict__ bgp,
                                          float* __restrict__ out, float* sm) {
    float* sBG = sm;
    __syncthreads();
    int b = w >> 9;
    for (int i = t; i < 2048; i += 256) sBG[i] = bgp[b * 2048 + i];
    __syncthreads();

    int off = (w & 511) * 2048 + t * 8;
    int Y = off >> 10, X0 = off & 1023;
    float fy = fminf(fmaxf((Y + 0.5f) * (1.0f / 64.0f) + 3.5f, 0.0f), 15.0f);
    float yf = floorf(fy);
    int yi = (int)yf;
    float ay = fy - yf;
    int yi1 = min(yi + 1, 15);

    uint4 qv = *(const uint4*)(gq + ((size_t)b << 20) + off);
    unsigned int qw[4] = {qv.x, qv.y, qv.z, qv.w};

    float val[8];
#pragma unroll
    for (int j = 0; j < 8; ++j) {
        unsigned int q = (qw[j >> 1] >> ((j & 1) * 16)) & 0xffff;
        float fz = (float)q * (1.0f / 8192.0f);
        int X = X0 + j;
        float fx = fminf(fmaxf((X + 0.5f) * (1.0f / 64.0f) + 3.5f, 0.0f), 15.0f);
        float xf = floorf(fx), zf = floorf(fz);
        int xi = (int)xf, zi = (int)zf;
        float ax = fx - xf, az = fz - zf;
        int xi1 = min(xi + 1, 15), zi1 = min(zi + 1, 7);

        const float* g0 = sBG + zi * 256;
        const float* g1p = sBG + zi1 * 256;
        int i00 = yi * 16 + xi, i01 = yi * 16 + xi1;
        int i10 = yi1 * 16 + xi, i11 = yi1 * 16 + xi1;
        float c00 = g0[i00] + az * (g1p[i00] - g0[i00]);
        float c01 = g0[i01] + az * (g1p[i01] - g0[i01]);
        float c10 = g0[i10] + az * (g1p[i10] - g0[i10]);
        float c11 = g0[i11] + az * (g1p[i11] - g0[i11]);
        float c0 = c00 + ay * (c10 - c00);
        float c1 = c01 + ay * (c11 - c01);
        val[j] = c0 + ax * (c1 - c0);
    }
    float4* op = (float4*)(out + ((size_t)b << 20) + off);
    op[0] = make_float4(val[0], val[1], val[2], val[3]);
    op[1] = make_float4(val[4], val[5], val[6], val[7]);
}

// ---------------------------------------------------------------------------
// THE mega kernel: whole pipeline, 12 stages, 11 software grid barriers.
// blur tiles (independent of lowres stream) are spread across S1..S6.
// ---------------------------------------------------------------------------
__global__ __launch_bounds__(256, 4) void mega_k(
    const float* __restrict__ lqs, const float* __restrict__ evs,
    const float* __restrict__ gw1, const float* __restrict__ gb1,
    const float* __restrict__ gw2, const float* __restrict__ gb2,
    const float* __restrict__ sw0, const float* __restrict__ sb0,
    const float* __restrict__ sw1, const float* __restrict__ sb1,
    const float* __restrict__ sw2, const float* __restrict__ sb2,
    const float* __restrict__ sw3, const float* __restrict__ sb3,
    const float* __restrict__ cw0, const float* __restrict__ cb0,
    const float* __restrict__ cw1, const float* __restrict__ cb1,
    const float* __restrict__ fw1, const float* __restrict__ fb1,
    const float* __restrict__ fw2, const float* __restrict__ fb2,
    const float* __restrict__ fw3, const float* __restrict__ fb3,
    const float* __restrict__ lw1, const float* __restrict__ lb1,
    const float* __restrict__ lw2,
    const float* __restrict__ fuw, const float* __restrict__ fub,
    float* __restrict__ o0, float* __restrict__ o1, float* __restrict__ o2,
    float* __restrict__ o3, float* __restrict__ xl1, float* __restrict__ xg0,
    float* __restrict__ h1, float* __restrict__ bg,
    float* __restrict__ partA, float* __restrict__ partB,
    float* __restrict__ partC, float* __restrict__ partD,
    unsigned short* __restrict__ gq, float* __restrict__ out,
    unsigned int* bar) {
    extern __shared__ float sm[];
    int blk = blockIdx.x, t = threadIdx.x;
    unsigned int* cnt = bar;
    unsigned int* gen = bar + 1;

    // S1: conv0 (128) + blur [0,1280)
    for (int w = blk; w < 1408; w += NB) {
        if (w < 128) dev_conv0(w * 256 + t, lqs, evs, sw0, sb0, o0);
        else dev_blur(w - 128, t, lqs, gw1, gb1, gw2, gb2, gq, sm);
    }
    gridbar(cnt, gen);
    // S2: conv1 (256) + blur [1280,2560)
    for (int w = blk; w < 1536; w += NB) {
        if (w < 256) dev_convN<8, 16, 8, 128, 128, 2, true, true>(w * 256 + t, o0, sw1, sb1, o1);
        else dev_blur(1280 + w - 256, t, lqs, gw1, gb1, gw2, gb2, gq, sm);
    }
    gridbar(cnt, gen);
    // S3: conv2 split-4 (512) + blur [2560,3072)
    for (int w = blk; w < 1024; w += NB) {
        if (w < 512) dev_convS<16, 32, 8, 64, 64, 2, 4>(w * 256 + t, o1, sw2, partA);
        else dev_blur(2560 + w - 512, t, lqs, gw1, gb1, gw2, gb2, gq, sm);
    }
    gridbar(cnt, gen);
    // S4: red2 (1024)
    for (int w = blk; w < 1024; w += NB)
        dev_reduce<32, 1024, 4, true, true>(w * 256 + t, partA, sb2, o2);
    gridbar(cnt, gen);
    // S5: conv3 split-8 (512) + blur [3072,3584)
    for (int w = blk; w < 1024; w += NB) {
        if (w < 512) dev_convS<32, 64, 8, 32, 32, 2, 8>(w * 256 + t, o2, sw3, partA);
        else dev_blur(3072 + w - 512, t, lqs, gw1, gb1, gw2, gb2, gq, sm);
    }
    gridbar(cnt, gen);
    // S6: red3 (512) + blur [3584,4096)
    for (int w = blk; w < 1024; w += NB) {
        if (w < 512) dev_reduce<64, 256, 8, true, true>(w * 256 + t, partA, sb3, o3);
        else dev_blur(3584 + w - 512, t, lqs, gw1, gb1, gw2, gb2, gq, sm);
    }
    gridbar(cnt, gen);
    // S7: lw1 split-8 (512) || cw0 split-16 (256)
    for (int w = blk; w < 768; w += NB) {
        if (w < 512) dev_convS<64, 64, 8, 16, 16, 1, 8>(w * 256 + t, o3, lw1, partA);
        else dev_convS<64, 64, 8, 16, 16, 2, 16>((w - 512) * 256 + t, o3, cw0, partB);
    }
    gridbar(cnt, gen);
    // S8: red lw1 (512) || red cw0 (128)
    for (int w = blk; w < 640; w += NB) {
        if (w < 512) dev_reduce<64, 256, 8, true, true>(w * 256 + t, partA, lb1, xl1);
        else dev_reduce<64, 64, 16, true, true>((w - 512) * 256 + t, partB, cb0, xg0);
    }
    gridbar(cnt, gen);
    // S9: lw2 split-8 (512) || cw1 split-16 (128)
    for (int w = blk; w < 640; w += NB) {
        if (w < 512) dev_convS<64, 64, 8, 16, 16, 1, 8>(w * 256 + t, xl1, lw2, partC);
        else dev_convS<64, 64, 4, 8, 8, 2, 16>((w - 512) * 256 + t, xg0, cw1, partD);
    }
    gridbar(cnt, gen);
    // S10: fc1 (512 works)
    for (int w = blk; w < 512; w += NB)
        dev_fc1(w, t, partD, cb1, fw1, fb1, h1, sm);
    gridbar(cnt, gen);
    // S11: fc23+fuse (64 works)
    for (int w = blk; w < 64; w += NB)
        dev_fc23fuse(w, t, h1, fw2, fb2, fw3, fb3, partC, fuw, fub, bg, sm);
    gridbar(cnt, gen);
    // S12: slice (4096 works)
    for (int w = blk; w < 4096; w += NB)
        dev_slice(w, t, gq, bg, out, sm);
}

// ---------------------------------------------------------------------------
extern "C" void kernel_launch(void* const* d_in, const int* in_sizes, int n_in,
                              void* d_out, int out_size, void* d_ws, size_t ws_size,
                              hipStream_t stream) {
    const float* lqs = (const float*)d_in[0];
    const float* evs = (const float*)d_in[1];
    const float* gw1 = (const float*)d_in[2];
    const float* gb1 = (const float*)d_in[3];
    const float* gw2 = (const float*)d_in[4];
    const float* gb2 = (const float*)d_in[5];
    const float* sw0 = (const float*)d_in[6];
    const float* sb0 = (const float*)d_in[7];
    const float* sw1 = (const float*)d_in[8];
    const float* sb1 = (const float*)d_in[9];
    const float* sw2 = (const float*)d_in[10];
    const float* sb2 = (const float*)d_in[11];
    const float* sw3 = (const float*)d_in[12];
    const float* sb3 = (const float*)d_in[13];
    const float* cw0 = (const float*)d_in[14];
    const float* cb0 = (const float*)d_in[15];
    const float* cw1 = (const float*)d_in[16];
    const float* cb1 = (const float*)d_in[17];
    const float* fw1 = (const float*)d_in[18];
    const float* fb1 = (const float*)d_in[19];
    const float* fw2 = (const float*)d_in[20];
    const float* fb2 = (const float*)d_in[21];
    const float* fw3 = (const float*)d_in[22];
    const float* fb3 = (const float*)d_in[23];
    const float* lw1 = (const float*)d_in[24];
    const float* lb1 = (const float*)d_in[25];
    const float* lw2 = (const float*)d_in[26];
    const float* fuw = (const float*)d_in[27];
    const float* fub = (const float*)d_in[28];
    float* out = (float*)d_out;

    float* ws = (float*)d_ws;
    float* o0 = ws;                        // 1048576
    float* o1 = o0 + 1048576;              //  524288
    float* o2 = o1 + 524288;               //  262144
    float* o3 = o2 + 262144;               //  131072
    float* xl1 = o3 + 131072;              //  131072
    float* xg0 = xl1 + 131072;             //   32768
    float* h1 = xg0 + 32768;               //    2048
    float* bg = h1 + 2048;                 //   16384
    float* partA = bg + 16384;             // 1048576
    float* partB = partA + 1048576;        //  524288
    float* partC = partB + 524288;         // 1048576
    float* partD = partC + 1048576;        //  131072
    unsigned int* bar = (unsigned int*)(partD + 131072);  // 2 uints (+pad 4)
    unsigned short* gq = (unsigned short*)(bar + 4);      // 8M u16 = 16.8 MB

    hipMemsetAsync(bar, 0, 16, stream);
    mega_k<<<NB, 256, 31488, stream>>>(
        lqs, evs, gw1, gb1, gw2, gb2, sw0, sb0, sw1, sb1, sw2, sb2, sw3, sb3,
        cw0, cb0, cw1, cb1, fw1, fb1, fw2, fb2, fw3, fb3, lw1, lb1, lw2,
        fuw, fub, o0, o1, o2, o3, xl1, xg0, h1, bg,
        partA, partB, partC, partD, gq, out, bar);
}